// Round 17
// baseline (122.337 us; speedup 1.0000x reference)
//
#include <hip/hip_runtime.h>
#include <hip/hip_bf16.h>
#include <math.h>

// Problem constants (B=1)
#define TT 2048
#define CC 768
#define NH 12
#define HDIM 64
#define QKVLD 2304   // 3*CC
#define NSEC 32      // TT/64
#define NCH 8        // key-sections per chunk
#define NCHMAX 4     // max chunks per query section (32/8)
#define NSLOTS 960   // sum over qsec of (qsec/8+1), x NH

typedef short bf16x8 __attribute__((ext_vector_type(8)));
typedef float f32x4 __attribute__((ext_vector_type(4)));

#define MFMA16(a, b, c) __builtin_amdgcn_mfma_f32_16x16x32_bf16(a, b, c, 0, 0, 0)

__device__ __forceinline__ ushort f2bf(float f) {
  __hip_bfloat16 h = __float2bfloat16(f);
  return *reinterpret_cast<ushort*>(&h);
}

__device__ __forceinline__ float bf2f(ushort u) {
  __hip_bfloat16 b = *reinterpret_cast<__hip_bfloat16*>(&u);
  return __bfloat162float(b);
}

__device__ __forceinline__ void gload_lds16(const ushort* g, ushort* l) {
  __builtin_amdgcn_global_load_lds(
      (const __attribute__((address_space(1))) void*)g,
      (__attribute__((address_space(3))) void*)l, 16, 0, 0);
}

// chunk_base(q) = sum_{j<q} (j/8+1) = q + 4a(a-1) + a*b,  a=q>>3, b=q&7
__device__ __forceinline__ int chunk_base(int q) {
  const int a = q >> 3, b = q & 7;
  return q + 4 * a * (a - 1) + a * b;
}

// ---------------------------------------------------------------------------
// Fused prep: blocks [0,768): x f32->bf16; [768,1200): w_qkv transpose;
// [1200,1344): w_proj transpose. f32 [K][N] -> bf16 [N][K] via 64x64 tiles.
// ---------------------------------------------------------------------------
__global__ __launch_bounds__(256) void prep_kernel(
    const float* __restrict__ x, const float* __restrict__ w_qkv,
    const float* __restrict__ w_proj,
    ushort* __restrict__ xb, ushort* __restrict__ wqkvT,
    ushort* __restrict__ wprojT) {
  const int bid = blockIdx.x;
  const int t = threadIdx.x;
  __shared__ float tile[64][65];

  if (bid < 768) {                     // ---- convert x ----
    const int i = (bid * 256 + t) * 8;
    float4 a = *(const float4*)&x[i];
    float4 b = *(const float4*)&x[i + 4];
    bf16x8 o;
    o[0] = (short)f2bf(a.x); o[1] = (short)f2bf(a.y);
    o[2] = (short)f2bf(a.z); o[3] = (short)f2bf(a.w);
    o[4] = (short)f2bf(b.x); o[5] = (short)f2bf(b.y);
    o[6] = (short)f2bf(b.z); o[7] = (short)f2bf(b.w);
    *(bf16x8*)&xb[i] = o;
    return;
  }

  const bool qkv = bid < 1200;
  const int tb = qkv ? bid - 768 : bid - 1200;
  const float* in = qkv ? w_qkv : w_proj;
  ushort* out = qkv ? wqkvT : wprojT;
  const int N = qkv ? QKVLD : CC;
  const int ntx = N / 64;
  const int nb = (tb % ntx) * 64, kb = (tb / ntx) * 64;
  const int K = CC;

  const int rg = t >> 4, cg = t & 15;
#pragma unroll
  for (int r = 0; r < 4; ++r) {
    float4 v = *(const float4*)&in[(size_t)(kb + rg * 4 + r) * N + nb + cg * 4];
    tile[rg * 4 + r][cg * 4 + 0] = v.x;
    tile[rg * 4 + r][cg * 4 + 1] = v.y;
    tile[rg * 4 + r][cg * 4 + 2] = v.z;
    tile[rg * 4 + r][cg * 4 + 3] = v.w;
  }
  __syncthreads();
#pragma unroll
  for (int r = 0; r < 4; ++r) {
    const int nl = rg * 4 + r;
    ushort4 o;
    o.x = f2bf(tile[cg * 4 + 0][nl]);
    o.y = f2bf(tile[cg * 4 + 1][nl]);
    o.z = f2bf(tile[cg * 4 + 2][nl]);
    o.w = f2bf(tile[cg * 4 + 3][nl]);
    *(ushort4*)&out[(size_t)(nb + nl) * K + kb + cg * 4] = o;
  }
}

// ---------------------------------------------------------------------------
// bf16 MFMA GEMM, 64x64 tile (B-transposed), double-buffered K-loop.
// LDS tiles 16B-granule XOR-swizzled, staged via global_load_lds with
// pre-swizzled source (r12-verified).
// ---------------------------------------------------------------------------
__global__ __launch_bounds__(256) void gemm_bt_bf16_kernel(
    const ushort* __restrict__ A, const ushort* __restrict__ Bt,
    const float* __restrict__ bias,
    ushort* __restrict__ qkvb, ushort* __restrict__ vT,
    float* __restrict__ Cf,
    int M, int N, int K) {
  __shared__ ushort As[2][64 * 64];
  __shared__ ushort Bs[2][64 * 64];
  const int tid = threadIdx.x;
  const int wid = tid >> 6, lane = tid & 63;
  const int lr = lane & 15, lg = lane >> 4;
  const int wr = wid >> 1, wc = wid & 1;
  const int bm = blockIdx.y * 64, bn = blockIdx.x * 64;

  f32x4 acc[2][2];
#pragma unroll
  for (int m = 0; m < 2; ++m)
#pragma unroll
    for (int n = 0; n < 2; ++n) acc[m][n] = (f32x4){0.f, 0.f, 0.f, 0.f};

  const int srow7 = lane >> 3;                // row&7 of staged row
  const int scolw = ((lane & 7) ^ srow7) * 8; // pre-swizzled source col
  const int rswz = lr & 7;                    // read-side swizzle

  // prologue: stage k0=0 into buf 0
#pragma unroll
  for (int half = 0; half < 2; ++half) {
    const int row = half * 32 + wid * 8 + srow7;
    gload_lds16(A  + (size_t)(bm + row) * K + scolw, &As[0][(half * 32 + wid * 8) * 64]);
    gload_lds16(Bt + (size_t)(bn + row) * K + scolw, &Bs[0][(half * 32 + wid * 8) * 64]);
  }
  int cur = 0;

  for (int k0 = 0; k0 < K; k0 += 64) {
    __syncthreads();
    if (k0 + 64 < K) {
      const int nb_ = cur ^ 1;
#pragma unroll
      for (int half = 0; half < 2; ++half) {
        const int row = half * 32 + wid * 8 + srow7;
        gload_lds16(A  + (size_t)(bm + row) * K + k0 + 64 + scolw,
                    &As[nb_][(half * 32 + wid * 8) * 64]);
        gload_lds16(Bt + (size_t)(bn + row) * K + k0 + 64 + scolw,
                    &Bs[nb_][(half * 32 + wid * 8) * 64]);
      }
    }
#pragma unroll
    for (int kk = 0; kk < 2; ++kk) {
      bf16x8 af[2], bfr[2];
#pragma unroll
      for (int m = 0; m < 2; ++m)
        af[m] = *(const bf16x8*)
            &As[cur][(wr * 32 + m * 16 + lr) * 64 + (((kk * 4 + lg) ^ rswz) * 8)];
#pragma unroll
      for (int n = 0; n < 2; ++n)
        bfr[n] = *(const bf16x8*)
            &Bs[cur][(wc * 32 + n * 16 + lr) * 64 + (((kk * 4 + lg) ^ rswz) * 8)];
#pragma unroll
      for (int m = 0; m < 2; ++m)
#pragma unroll
        for (int n = 0; n < 2; ++n)
          acc[m][n] = MFMA16(af[m], bfr[n], acc[m][n]);
    }
    cur ^= 1;
  }

  float bb[2];
#pragma unroll
  for (int n = 0; n < 2; ++n) bb[n] = bias[bn + wc * 32 + n * 16 + lr];

  if (Cf) {
#pragma unroll
    for (int m = 0; m < 2; ++m)
#pragma unroll
      for (int n = 0; n < 2; ++n)
#pragma unroll
        for (int r = 0; r < 4; ++r) {
          const int row = bm + wr * 32 + m * 16 + lg * 4 + r;
          const int col = bn + wc * 32 + n * 16 + lr;
          Cf[(size_t)row * N + col] = acc[m][n][r] + bb[n];
        }
  } else if (bn < 768) {          // Q (scaled by 1/8)
#pragma unroll
    for (int m = 0; m < 2; ++m)
#pragma unroll
      for (int n = 0; n < 2; ++n)
#pragma unroll
        for (int r = 0; r < 4; ++r) {
          const int row = bm + wr * 32 + m * 16 + lg * 4 + r;
          const int col = bn + wc * 32 + n * 16 + lr;
          qkvb[(size_t)row * QKVLD + col] = f2bf((acc[m][n][r] + bb[n]) * 0.125f);
        }
  } else if (bn < 1536) {         // K
#pragma unroll
    for (int m = 0; m < 2; ++m)
#pragma unroll
      for (int n = 0; n < 2; ++n)
#pragma unroll
        for (int r = 0; r < 4; ++r) {
          const int row = bm + wr * 32 + m * 16 + lg * 4 + r;
          const int col = bn + wc * 32 + n * 16 + lr;
          qkvb[(size_t)row * QKVLD + col] = f2bf(acc[m][n][r] + bb[n]);
        }
  } else {                        // V -> transposed
#pragma unroll
    for (int m = 0; m < 2; ++m)
#pragma unroll
      for (int n = 0; n < 2; ++n) {
        const int row0 = bm + wr * 32 + m * 16 + lg * 4;
        const int vrow = bn + wc * 32 + n * 16 + lr - 1536;
        ushort4 o;
        o.x = f2bf(acc[m][n][0] + bb[n]);
        o.y = f2bf(acc[m][n][1] + bb[n]);
        o.z = f2bf(acc[m][n][2] + bb[n]);
        o.w = f2bf(acc[m][n][3] + bb[n]);
        *(ushort4*)&vT[(size_t)vrow * TT + row0] = o;
      }
  }
}

// ---------------------------------------------------------------------------
// Landmark grouped-softmax attention, CHUNKED (8 sections/block),
// fully-swapped (S^T and O^T), REG-STAGED single-buffer K/V:
// barrier -> ds_write regs->LDS -> barrier -> issue next global loads ->
// compute (loads land under the ~1200-cyc compute). LDS 24KB -> 6 blocks/CU
// (vs 40KB dbuf / 4 blocks). Swizzled LDS layout identical to r12
// (linear dest = base + lane*16B; source pre-swizzled).
// ---------------------------------------------------------------------------
__global__ __launch_bounds__(256, 6) void attn_chunk_kernel(
    const ushort* __restrict__ qkvb,  // [2048][2304] bf16 (Q pre-scaled)
    const ushort* __restrict__ vT,    // [768][2048]  bf16 (V transposed)
    ushort* __restrict__ pacc,        // [slot][64 d][64 q]  bf16
    float* __restrict__ pstats) {     // [slot][64 q][2]  (m, dl)
  const int c = blockIdx.x, qsec = blockIdx.y, h = blockIdx.z;
  if (c * NCH > qsec) return;
  const int tid = threadIdx.x;
  const int wid = tid >> 6, lane = tid & 63;
  const int lr = lane & 15, lg = lane >> 4;

  __shared__ ushort Kl[64 * 64];       // [key][d], swizzled
  __shared__ ushort Vl[64 * 64];       // [d][key], swizzled
  __shared__ ushort Pl[4 * 16 * 64];   // [wave][q][key], swizzled

  const int qloc = wid * 16 + lr;    // this lane's query (all state lane-local)
  const ushort* qp = qkvb + (size_t)(qsec * 64 + qloc) * QKVLD + h * HDIM + lg * 8;
  const bf16x8 qf0 = *(const bf16x8*)qp;
  const bf16x8 qf1 = *(const bf16x8*)(qp + 32);

  f32x4 accy[4];                     // O^T[d=nt*16+lg*4+r][q=lr]
#pragma unroll
  for (int nt = 0; nt < 4; ++nt) accy[nt] = (f32x4){0.f, 0.f, 0.f, 0.f};
  float mrun = -INFINITY, dl = 0.f;

  const int s0 = c * NCH;
  const int send = (s0 + NCH - 1 < qsec) ? s0 + NCH - 1 : qsec;

  // staging addressing (same layout gload_lds produced: dest = base+lane*16B)
  const int srow = wid * 8 + (lane >> 3);
  const int scolw = ((lane & 7) ^ (lane >> 3)) * 8;  // pre-swizzled source col
  const int dstoff = wid * 512 + lane * 8;           // ushort offset in tile
  const ushort* ksrc = qkvb + (size_t)(s0 * 64 + srow) * QKVLD + CC + h * HDIM + scolw;
  const ushort* vsrc = vT + (size_t)(h * HDIM + srow) * TT + s0 * 64 + scolw;
  const int rswz = lr & 7;

  // prologue: load section s0 into staging registers
  bf16x8 kr0 = *(const bf16x8*)ksrc;
  bf16x8 kr1 = *(const bf16x8*)(ksrc + (size_t)32 * QKVLD);
  bf16x8 vr0 = *(const bf16x8*)vsrc;
  bf16x8 vr1 = *(const bf16x8*)(vsrc + (size_t)32 * TT);

  for (int s = s0; s <= send; ++s) {
    __syncthreads();                 // all waves done reading Kl/Vl (prev s)
    *(bf16x8*)&Kl[dstoff]        = kr0;
    *(bf16x8*)&Kl[dstoff + 2048] = kr1;
    *(bf16x8*)&Vl[dstoff]        = vr0;
    *(bf16x8*)&Vl[dstoff + 2048] = vr1;
    __syncthreads();                 // staging visible
    if (s < send) {                  // issue next section's loads early;
      ksrc += (size_t)64 * QKVLD;    // they complete under compute(s)
      vsrc += 64;
      kr0 = *(const bf16x8*)ksrc;
      kr1 = *(const bf16x8*)(ksrc + (size_t)32 * QKVLD);
      vr0 = *(const bf16x8*)vsrc;
      vr1 = *(const bf16x8*)(vsrc + (size_t)32 * TT);
    }

    // ---- S^T = K @ Q^T ----
    f32x4 sacc[4];
#pragma unroll
    for (int nt = 0; nt < 4; ++nt) sacc[nt] = (f32x4){0.f, 0.f, 0.f, 0.f};
#pragma unroll
    for (int nt = 0; nt < 4; ++nt) {
      bf16x8 kf0 = *(const bf16x8*)&Kl[(nt * 16 + lr) * 64 + ((lg ^ rswz) * 8)];
      bf16x8 kf1 = *(const bf16x8*)&Kl[(nt * 16 + lr) * 64 + (((4 + lg) ^ rswz) * 8)];
      sacc[nt] = MFMA16(kf0, qf0, sacc[nt]);
      sacc[nt] = MFMA16(kf1, qf1, sacc[nt]);
    }

    const bool curq = (s == qsec);
    float lmv = 0.f;
    if (!curq) {
      lmv = __shfl(sacc[3][3], 48 + lr);     // landmark logit for query lr
      if (lg == 3) sacc[3][3] = -INFINITY;   // exclude landmark from bucket s
    } else {
      const int lim = qloc < 62 ? qloc : 62; // causal + own-landmark mask
#pragma unroll
      for (int nt = 0; nt < 4; ++nt)
#pragma unroll
        for (int r = 0; r < 4; ++r)
          if (nt * 16 + lg * 4 + r > lim) sacc[nt][r] = -INFINITY;
    }

    // ---- per-query max (in-lane + xor16 + xor32) ----
    float vmax = sacc[0][0];
#pragma unroll
    for (int nt = 0; nt < 4; ++nt)
#pragma unroll
      for (int r = 0; r < 4; ++r) vmax = fmaxf(vmax, sacc[nt][r]);
    vmax = fmaxf(vmax, __shfl_xor(vmax, 16));
    vmax = fmaxf(vmax, __shfl_xor(vmax, 32));

    float base_;
    if (curq) {
      float mn = fmaxf(mrun, vmax);
      float sc = __expf(mrun - mn);
#pragma unroll
      for (int nt = 0; nt < 4; ++nt) accy[nt] *= sc;   // lane-local rescale
      dl *= sc; mrun = mn; base_ = mn;
    } else {
      base_ = vmax;
    }

    // ---- exp + per-query sum ----
    float ssum = 0.f;
#pragma unroll
    for (int nt = 0; nt < 4; ++nt)
#pragma unroll
      for (int r = 0; r < 4; ++r) {
        sacc[nt][r] = __expf(sacc[nt][r] - base_);
        ssum += sacc[nt][r];
      }
    ssum += __shfl_xor(ssum, 16);
    ssum += __shfl_xor(ssum, 32);

    float coef;
    if (!curq) {
      float mn = fmaxf(mrun, lmv);
      float sc = __expf(mrun - mn);
      float el = __expf(lmv - mn);
#pragma unroll
      for (int nt = 0; nt < 4; ++nt) accy[nt] *= sc;   // lane-local rescale
      dl = dl * sc + el; mrun = mn;
      coef = el / ssum;              // fold p63(lm_s)/d_s into P
    } else {
      coef = 1.f;
      dl += ssum;
    }

    // ---- P pack -> Pl[wid][q=lr], swizzled granule (nt*2+(lg>>1))^rswz ----
    {
      ushort* prow = &Pl[wid * 1024 + lr * 64];
#pragma unroll
      for (int nt = 0; nt < 4; ++nt) {
        ushort4 o;
        o.x = f2bf(sacc[nt][0] * coef);
        o.y = f2bf(sacc[nt][1] * coef);
        o.z = f2bf(sacc[nt][2] * coef);
        o.w = f2bf(sacc[nt][3] * coef);
        *(ushort4*)&prow[(((nt * 2 + (lg >> 1)) ^ rswz) * 8) + (lg & 1) * 4] = o;
      }

      // ---- O^T += Vt @ P^T ----
      bf16x8 pf0 = *(const bf16x8*)&prow[(lg ^ rswz) * 8];
      bf16x8 pf1 = *(const bf16x8*)&prow[((4 + lg) ^ rswz) * 8];
#pragma unroll
      for (int nt = 0; nt < 4; ++nt) {
        bf16x8 vf0 = *(const bf16x8*)&Vl[(nt * 16 + lr) * 64 + ((lg ^ rswz) * 8)];
        bf16x8 vf1 = *(const bf16x8*)&Vl[(nt * 16 + lr) * 64 + (((4 + lg) ^ rswz) * 8)];
        accy[nt] = MFMA16(vf0, pf0, accy[nt]);
        accy[nt] = MFMA16(vf1, pf1, accy[nt]);
      }
    }
  }

  // ---- write partial state: pacc[slot][d][q] bf16, stats per q ----
  const int slot = (chunk_base(qsec) + c) * NH + h;
  ushort* ap = pacc + (size_t)slot * 4096;
#pragma unroll
  for (int nt = 0; nt < 4; ++nt)
#pragma unroll
    for (int r = 0; r < 4; ++r)
      ap[(nt * 16 + lg * 4 + r) * 64 + wid * 16 + lr] = f2bf(accy[nt][r]);
  if (lg == 0) {
    float* st = pstats + (size_t)slot * 128;
    st[(wid * 16 + lr) * 2 + 0] = mrun;
    st[(wid * 16 + lr) * 2 + 1] = dl;
  }
}

// ---------------------------------------------------------------------------
// Merge partials ([d][q] bf16) -> y[t][h*64+d] bf16.  nch <= 4.
// ---------------------------------------------------------------------------
__global__ __launch_bounds__(256) void attn_merge_kernel(
    const ushort* __restrict__ pacc, const float* __restrict__ pstats,
    ushort* __restrict__ y) {
  const int qsec = blockIdx.x, h = blockIdx.y;
  const int tid = threadIdx.x;
  const int w = tid >> 6, q = tid & 63;
  const int nch = (qsec >> 3) + 1;
  const int sbase = chunk_base(qsec);
  __shared__ float Lt[64][65];   // [d][q]

  float M = -INFINITY;
  for (int cc = 0; cc < nch; ++cc)
    M = fmaxf(M, pstats[(size_t)((sbase + cc) * NH + h) * 128 + q * 2]);
  float D = 0.f;
  for (int cc = 0; cc < nch; ++cc) {
    const float* st = pstats + (size_t)((sbase + cc) * NH + h) * 128 + q * 2;
    D += __expf(st[0] - M) * st[1];
  }
  const float invD = 1.f / D;

  float val[16];
#pragma unroll
  for (int j = 0; j < 16; ++j) val[j] = 0.f;
  for (int cc = 0; cc < nch; ++cc) {
    const int slot = (sbase + cc) * NH + h;
    const float cw = __expf(pstats[(size_t)slot * 128 + q * 2] - M) * invD;
    const ushort* ap = pacc + (size_t)slot * 4096 + w * 16 * 64 + q;
#pragma unroll
    for (int j = 0; j < 16; ++j) val[j] += cw * bf2f(ap[j * 64]);
  }
#pragma unroll
  for (int j = 0; j < 16; ++j) Lt[w * 16 + j][q] = val[j];
  __syncthreads();

  const int d = tid & 63;
#pragma unroll
  for (int j = 0; j < 16; ++j) {
    const int qq = w * 16 + j;
    y[(size_t)(qsec * 64 + qq) * CC + h * HDIM + d] = f2bf(Lt[d][qq]);
  }
}

// ---------------------------------------------------------------------------
extern "C" void kernel_launch(void* const* d_in, const int* in_sizes, int n_in,
                              void* d_out, int out_size, void* d_ws, size_t ws_size,
                              hipStream_t stream) {
  const float* x      = (const float*)d_in[0];
  // d_in[1] = is_mem: deterministic (t%64==63), recomputed in-kernel.
  const float* w_qkv  = (const float*)d_in[2];
  const float* b_qkv  = (const float*)d_in[3];
  const float* w_proj = (const float*)d_in[4];
  const float* b_proj = (const float*)d_in[5];
  float* out = (float*)d_out;

  // ws layout (bf16 elems unless noted). xb/wqkvT alias pacc (dead once the
  // qkv GEMM completes; stream is serial). pacc = 960*4096*2 = 7.86 MB >
  // xb+wqkvT = 6.7 MB, so the alias still fits.
  ushort* wprojT = (ushort*)d_ws;                     // 768 x 768
  ushort* qkvb   = wprojT + (size_t)CC * CC;          // 2048 x 2304
  ushort* vT     = qkvb + (size_t)TT * QKVLD;         // 768 x 2048
  ushort* y      = vT + (size_t)CC * TT;              // 2048 x 768
  ushort* pacc   = y + (size_t)TT * CC;               // 960 x 4096 bf16
  float*  pstats = (float*)(pacc + (size_t)NSLOTS * 4096);  // 960 x 128 f32
  ushort* xb     = pacc;                              // alias: 2048 x 768
  ushort* wqkvT  = xb + (size_t)TT * CC;              // alias: 2304 x 768

  // fused prep: convert x + both weight transposes
  prep_kernel<<<1344, 256, 0, stream>>>(x, w_qkv, w_proj, xb, wqkvT, wprojT);

  // qkv = xb @ wqkvT^T + b_qkv  (bf16 out, Q scaled, V transposed)
  gemm_bt_bf16_kernel<<<dim3(QKVLD / 64, TT / 64), 256, 0, stream>>>(
      xb, wqkvT, b_qkv, qkvb, vT, nullptr, TT, QKVLD, CC);

  // chunked landmark attention + merge
  attn_chunk_kernel<<<dim3(NCHMAX, NSEC, NH), 256, 0, stream>>>(
      qkvb, vT, pacc, pstats);
  attn_merge_kernel<<<dim3(NSEC, NH), 256, 0, stream>>>(pacc, pstats, y);

  // out = y @ wprojT^T + b_proj  (f32 out)
  gemm_bt_bf16_kernel<<<dim3(CC / 64, TT / 64), 256, 0, stream>>>(
      y, wprojT, b_proj, nullptr, nullptr, out, TT, CC, CC);
}

// Round 18
// 76.713 us; speedup vs baseline: 1.5947x; 1.5947x over previous
//
#include <hip/hip_runtime.h>
#include <hip/hip_bf16.h>
#include <math.h>

// Problem constants (B=1)
#define TT 2048
#define CC 768
#define NH 12
#define HDIM 64
#define QKVLD 2304   // 3*CC
#define NSEC 32      // TT/64
#define NCH 8        // key-sections per chunk
#define NCHMAX 4     // max chunks per query section (32/8)
#define NSLOTS 960   // sum over qsec of (qsec/8+1), x NH

typedef short bf16x8 __attribute__((ext_vector_type(8)));
typedef float f32x4 __attribute__((ext_vector_type(4)));

#define MFMA16(a, b, c) __builtin_amdgcn_mfma_f32_16x16x32_bf16(a, b, c, 0, 0, 0)

__device__ __forceinline__ ushort f2bf(float f) {
  __hip_bfloat16 h = __float2bfloat16(f);
  return *reinterpret_cast<ushort*>(&h);
}

__device__ __forceinline__ float bf2f(ushort u) {
  __hip_bfloat16 b = *reinterpret_cast<__hip_bfloat16*>(&u);
  return __bfloat162float(b);
}

__device__ __forceinline__ void gload_lds16(const ushort* g, ushort* l) {
  __builtin_amdgcn_global_load_lds(
      (const __attribute__((address_space(1))) void*)g,
      (__attribute__((address_space(3))) void*)l, 16, 0, 0);
}

// chunk_base(q) = sum_{j<q} (j/8+1) = q + 4a(a-1) + a*b,  a=q>>3, b=q&7
__device__ __forceinline__ int chunk_base(int q) {
  const int a = q >> 3, b = q & 7;
  return q + 4 * a * (a - 1) + a * b;
}

// ---------------------------------------------------------------------------
// Fused prep: blocks [0,768): x f32->bf16; [768,1200): w_qkv transpose;
// [1200,1344): w_proj transpose. f32 [K][N] -> bf16 [N][K] via 64x64 tiles.
// ---------------------------------------------------------------------------
__global__ __launch_bounds__(256) void prep_kernel(
    const float* __restrict__ x, const float* __restrict__ w_qkv,
    const float* __restrict__ w_proj,
    ushort* __restrict__ xb, ushort* __restrict__ wqkvT,
    ushort* __restrict__ wprojT) {
  const int bid = blockIdx.x;
  const int t = threadIdx.x;
  __shared__ float tile[64][65];

  if (bid < 768) {                     // ---- convert x ----
    const int i = (bid * 256 + t) * 8;
    float4 a = *(const float4*)&x[i];
    float4 b = *(const float4*)&x[i + 4];
    bf16x8 o;
    o[0] = (short)f2bf(a.x); o[1] = (short)f2bf(a.y);
    o[2] = (short)f2bf(a.z); o[3] = (short)f2bf(a.w);
    o[4] = (short)f2bf(b.x); o[5] = (short)f2bf(b.y);
    o[6] = (short)f2bf(b.z); o[7] = (short)f2bf(b.w);
    *(bf16x8*)&xb[i] = o;
    return;
  }

  const bool qkv = bid < 1200;
  const int tb = qkv ? bid - 768 : bid - 1200;
  const float* in = qkv ? w_qkv : w_proj;
  ushort* out = qkv ? wqkvT : wprojT;
  const int N = qkv ? QKVLD : CC;
  const int ntx = N / 64;
  const int nb = (tb % ntx) * 64, kb = (tb / ntx) * 64;
  const int K = CC;

  const int rg = t >> 4, cg = t & 15;
#pragma unroll
  for (int r = 0; r < 4; ++r) {
    float4 v = *(const float4*)&in[(size_t)(kb + rg * 4 + r) * N + nb + cg * 4];
    tile[rg * 4 + r][cg * 4 + 0] = v.x;
    tile[rg * 4 + r][cg * 4 + 1] = v.y;
    tile[rg * 4 + r][cg * 4 + 2] = v.z;
    tile[rg * 4 + r][cg * 4 + 3] = v.w;
  }
  __syncthreads();
#pragma unroll
  for (int r = 0; r < 4; ++r) {
    const int nl = rg * 4 + r;
    ushort4 o;
    o.x = f2bf(tile[cg * 4 + 0][nl]);
    o.y = f2bf(tile[cg * 4 + 1][nl]);
    o.z = f2bf(tile[cg * 4 + 2][nl]);
    o.w = f2bf(tile[cg * 4 + 3][nl]);
    *(ushort4*)&out[(size_t)(nb + nl) * K + kb + cg * 4] = o;
  }
}

// ---------------------------------------------------------------------------
// bf16 MFMA GEMM, 64x64 tile (B-transposed), double-buffered K-loop.
// LDS tiles 16B-granule XOR-swizzled, staged via global_load_lds with
// pre-swizzled source (r12-verified).
// ---------------------------------------------------------------------------
__global__ __launch_bounds__(256) void gemm_bt_bf16_kernel(
    const ushort* __restrict__ A, const ushort* __restrict__ Bt,
    const float* __restrict__ bias,
    ushort* __restrict__ qkvb, ushort* __restrict__ vT,
    float* __restrict__ Cf,
    int M, int N, int K) {
  __shared__ ushort As[2][64 * 64];
  __shared__ ushort Bs[2][64 * 64];
  const int tid = threadIdx.x;
  const int wid = tid >> 6, lane = tid & 63;
  const int lr = lane & 15, lg = lane >> 4;
  const int wr = wid >> 1, wc = wid & 1;
  const int bm = blockIdx.y * 64, bn = blockIdx.x * 64;

  f32x4 acc[2][2];
#pragma unroll
  for (int m = 0; m < 2; ++m)
#pragma unroll
    for (int n = 0; n < 2; ++n) acc[m][n] = (f32x4){0.f, 0.f, 0.f, 0.f};

  const int srow7 = lane >> 3;                // row&7 of staged row
  const int scolw = ((lane & 7) ^ srow7) * 8; // pre-swizzled source col
  const int rswz = lr & 7;                    // read-side swizzle

  // prologue: stage k0=0 into buf 0
#pragma unroll
  for (int half = 0; half < 2; ++half) {
    const int row = half * 32 + wid * 8 + srow7;
    gload_lds16(A  + (size_t)(bm + row) * K + scolw, &As[0][(half * 32 + wid * 8) * 64]);
    gload_lds16(Bt + (size_t)(bn + row) * K + scolw, &Bs[0][(half * 32 + wid * 8) * 64]);
  }
  int cur = 0;

  for (int k0 = 0; k0 < K; k0 += 64) {
    __syncthreads();
    if (k0 + 64 < K) {
      const int nb_ = cur ^ 1;
#pragma unroll
      for (int half = 0; half < 2; ++half) {
        const int row = half * 32 + wid * 8 + srow7;
        gload_lds16(A  + (size_t)(bm + row) * K + k0 + 64 + scolw,
                    &As[nb_][(half * 32 + wid * 8) * 64]);
        gload_lds16(Bt + (size_t)(bn + row) * K + k0 + 64 + scolw,
                    &Bs[nb_][(half * 32 + wid * 8) * 64]);
      }
    }
#pragma unroll
    for (int kk = 0; kk < 2; ++kk) {
      bf16x8 af[2], bfr[2];
#pragma unroll
      for (int m = 0; m < 2; ++m)
        af[m] = *(const bf16x8*)
            &As[cur][(wr * 32 + m * 16 + lr) * 64 + (((kk * 4 + lg) ^ rswz) * 8)];
#pragma unroll
      for (int n = 0; n < 2; ++n)
        bfr[n] = *(const bf16x8*)
            &Bs[cur][(wc * 32 + n * 16 + lr) * 64 + (((kk * 4 + lg) ^ rswz) * 8)];
#pragma unroll
      for (int m = 0; m < 2; ++m)
#pragma unroll
        for (int n = 0; n < 2; ++n)
          acc[m][n] = MFMA16(af[m], bfr[n], acc[m][n]);
    }
    cur ^= 1;
  }

  float bb[2];
#pragma unroll
  for (int n = 0; n < 2; ++n) bb[n] = bias[bn + wc * 32 + n * 16 + lr];

  if (Cf) {
#pragma unroll
    for (int m = 0; m < 2; ++m)
#pragma unroll
      for (int n = 0; n < 2; ++n)
#pragma unroll
        for (int r = 0; r < 4; ++r) {
          const int row = bm + wr * 32 + m * 16 + lg * 4 + r;
          const int col = bn + wc * 32 + n * 16 + lr;
          Cf[(size_t)row * N + col] = acc[m][n][r] + bb[n];
        }
  } else if (bn < 768) {          // Q (scaled by 1/8)
#pragma unroll
    for (int m = 0; m < 2; ++m)
#pragma unroll
      for (int n = 0; n < 2; ++n)
#pragma unroll
        for (int r = 0; r < 4; ++r) {
          const int row = bm + wr * 32 + m * 16 + lg * 4 + r;
          const int col = bn + wc * 32 + n * 16 + lr;
          qkvb[(size_t)row * QKVLD + col] = f2bf((acc[m][n][r] + bb[n]) * 0.125f);
        }
  } else if (bn < 1536) {         // K
#pragma unroll
    for (int m = 0; m < 2; ++m)
#pragma unroll
      for (int n = 0; n < 2; ++n)
#pragma unroll
        for (int r = 0; r < 4; ++r) {
          const int row = bm + wr * 32 + m * 16 + lg * 4 + r;
          const int col = bn + wc * 32 + n * 16 + lr;
          qkvb[(size_t)row * QKVLD + col] = f2bf(acc[m][n][r] + bb[n]);
        }
  } else {                        // V -> transposed
#pragma unroll
    for (int m = 0; m < 2; ++m)
#pragma unroll
      for (int n = 0; n < 2; ++n) {
        const int row0 = bm + wr * 32 + m * 16 + lg * 4;
        const int vrow = bn + wc * 32 + n * 16 + lr - 1536;
        ushort4 o;
        o.x = f2bf(acc[m][n][0] + bb[n]);
        o.y = f2bf(acc[m][n][1] + bb[n]);
        o.z = f2bf(acc[m][n][2] + bb[n]);
        o.w = f2bf(acc[m][n][3] + bb[n]);
        *(ushort4*)&vT[(size_t)vrow * TT + row0] = o;
      }
  }
}

// ---------------------------------------------------------------------------
// Landmark grouped-softmax attention, CHUNKED (8 sections/block),
// fully-swapped (S^T and O^T), double-buffered K/V staging, swizzled LDS,
// lane-local softmax. (256,4): 128-VGPR budget, 4 blocks/CU (LDS-capped) --
// the measured optimum; (256,6)+reg-staging spills catastrophically (r17).
// ---------------------------------------------------------------------------
__global__ __launch_bounds__(256, 4) void attn_chunk_kernel(
    const ushort* __restrict__ qkvb,  // [2048][2304] bf16 (Q pre-scaled)
    const ushort* __restrict__ vT,    // [768][2048]  bf16 (V transposed)
    ushort* __restrict__ pacc,        // [slot][64 d][64 q]  bf16
    float* __restrict__ pstats) {     // [slot][64 q][2]  (m, dl)
  const int c = blockIdx.x, qsec = blockIdx.y, h = blockIdx.z;
  if (c * NCH > qsec) return;
  const int tid = threadIdx.x;
  const int wid = tid >> 6, lane = tid & 63;
  const int lr = lane & 15, lg = lane >> 4;

  __shared__ ushort Kl[2][64 * 64];    // [buf][key][d], swizzled
  __shared__ ushort Vl[2][64 * 64];    // [buf][d][key], swizzled
  __shared__ ushort Pl[4 * 16 * 64];   // [wave][q][key], swizzled

  const int qloc = wid * 16 + lr;    // this lane's query (all state lane-local)
  const ushort* qp = qkvb + (size_t)(qsec * 64 + qloc) * QKVLD + h * HDIM + lg * 8;
  const bf16x8 qf0 = *(const bf16x8*)qp;
  const bf16x8 qf1 = *(const bf16x8*)(qp + 32);

  f32x4 accy[4];                     // O^T[d=nt*16+lg*4+r][q=lr]
#pragma unroll
  for (int nt = 0; nt < 4; ++nt) accy[nt] = (f32x4){0.f, 0.f, 0.f, 0.f};
  float mrun = -INFINITY, dl = 0.f;

  const int s0 = c * NCH;
  const int send = (s0 + NCH - 1 < qsec) ? s0 + NCH - 1 : qsec;

  const int srow = wid * 8 + (lane >> 3);
  const int scolw = ((lane & 7) ^ (lane >> 3)) * 8;
  const ushort* ksrc = qkvb + (size_t)(s0 * 64 + srow) * QKVLD + CC + h * HDIM + scolw;
  const ushort* vsrc = vT + (size_t)(h * HDIM + srow) * TT + s0 * 64 + scolw;
  const int rswz = lr & 7;

  // prologue: stage section s0 into buf 0
  gload_lds16(ksrc,                      &Kl[0][wid * 512]);
  gload_lds16(ksrc + (size_t)32 * QKVLD, &Kl[0][wid * 512 + 2048]);
  gload_lds16(vsrc,                      &Vl[0][wid * 512]);
  gload_lds16(vsrc + (size_t)32 * TT,    &Vl[0][wid * 512 + 2048]);
  int cur = 0;

  for (int s = s0; s <= send; ++s) {
    __syncthreads();
    if (s < send) {
      ksrc += (size_t)64 * QKVLD;
      vsrc += 64;
      const int nb_ = cur ^ 1;
      gload_lds16(ksrc,                      &Kl[nb_][wid * 512]);
      gload_lds16(ksrc + (size_t)32 * QKVLD, &Kl[nb_][wid * 512 + 2048]);
      gload_lds16(vsrc,                      &Vl[nb_][wid * 512]);
      gload_lds16(vsrc + (size_t)32 * TT,    &Vl[nb_][wid * 512 + 2048]);
    }

    // ---- S^T = K @ Q^T ----
    f32x4 sacc[4];
#pragma unroll
    for (int nt = 0; nt < 4; ++nt) sacc[nt] = (f32x4){0.f, 0.f, 0.f, 0.f};
#pragma unroll
    for (int nt = 0; nt < 4; ++nt) {
      bf16x8 kf0 = *(const bf16x8*)&Kl[cur][(nt * 16 + lr) * 64 + ((lg ^ rswz) * 8)];
      bf16x8 kf1 = *(const bf16x8*)&Kl[cur][(nt * 16 + lr) * 64 + (((4 + lg) ^ rswz) * 8)];
      sacc[nt] = MFMA16(kf0, qf0, sacc[nt]);
      sacc[nt] = MFMA16(kf1, qf1, sacc[nt]);
    }

    const bool curq = (s == qsec);
    float lmv = 0.f;
    if (!curq) {
      lmv = __shfl(sacc[3][3], 48 + lr);     // landmark logit for query lr
      if (lg == 3) sacc[3][3] = -INFINITY;   // exclude landmark from bucket s
    } else {
      const int lim = qloc < 62 ? qloc : 62; // causal + own-landmark mask
#pragma unroll
      for (int nt = 0; nt < 4; ++nt)
#pragma unroll
        for (int r = 0; r < 4; ++r)
          if (nt * 16 + lg * 4 + r > lim) sacc[nt][r] = -INFINITY;
    }

    // ---- per-query max (in-lane + xor16 + xor32) ----
    float vmax = sacc[0][0];
#pragma unroll
    for (int nt = 0; nt < 4; ++nt)
#pragma unroll
      for (int r = 0; r < 4; ++r) vmax = fmaxf(vmax, sacc[nt][r]);
    vmax = fmaxf(vmax, __shfl_xor(vmax, 16));
    vmax = fmaxf(vmax, __shfl_xor(vmax, 32));

    float base_;
    if (curq) {
      float mn = fmaxf(mrun, vmax);
      float sc = __expf(mrun - mn);
#pragma unroll
      for (int nt = 0; nt < 4; ++nt) accy[nt] *= sc;   // lane-local rescale
      dl *= sc; mrun = mn; base_ = mn;
    } else {
      base_ = vmax;
    }

    // ---- exp + per-query sum ----
    float ssum = 0.f;
#pragma unroll
    for (int nt = 0; nt < 4; ++nt)
#pragma unroll
      for (int r = 0; r < 4; ++r) {
        sacc[nt][r] = __expf(sacc[nt][r] - base_);
        ssum += sacc[nt][r];
      }
    ssum += __shfl_xor(ssum, 16);
    ssum += __shfl_xor(ssum, 32);

    float coef;
    if (!curq) {
      float mn = fmaxf(mrun, lmv);
      float sc = __expf(mrun - mn);
      float el = __expf(lmv - mn);
#pragma unroll
      for (int nt = 0; nt < 4; ++nt) accy[nt] *= sc;   // lane-local rescale
      dl = dl * sc + el; mrun = mn;
      coef = el / ssum;              // fold p63(lm_s)/d_s into P
    } else {
      coef = 1.f;
      dl += ssum;
    }

    // ---- P pack -> Pl[wid][q=lr], swizzled granule (nt*2+(lg>>1))^rswz ----
    {
      ushort* prow = &Pl[wid * 1024 + lr * 64];
#pragma unroll
      for (int nt = 0; nt < 4; ++nt) {
        ushort4 o;
        o.x = f2bf(sacc[nt][0] * coef);
        o.y = f2bf(sacc[nt][1] * coef);
        o.z = f2bf(sacc[nt][2] * coef);
        o.w = f2bf(sacc[nt][3] * coef);
        *(ushort4*)&prow[(((nt * 2 + (lg >> 1)) ^ rswz) * 8) + (lg & 1) * 4] = o;
      }

      // ---- O^T += Vt @ P^T ----
      bf16x8 pf0 = *(const bf16x8*)&prow[(lg ^ rswz) * 8];
      bf16x8 pf1 = *(const bf16x8*)&prow[((4 + lg) ^ rswz) * 8];
#pragma unroll
      for (int nt = 0; nt < 4; ++nt) {
        bf16x8 vf0 = *(const bf16x8*)&Vl[cur][(nt * 16 + lr) * 64 + ((lg ^ rswz) * 8)];
        bf16x8 vf1 = *(const bf16x8*)&Vl[cur][(nt * 16 + lr) * 64 + (((4 + lg) ^ rswz) * 8)];
        accy[nt] = MFMA16(vf0, pf0, accy[nt]);
        accy[nt] = MFMA16(vf1, pf1, accy[nt]);
      }
    }
    cur ^= 1;
  }

  // ---- write partial state: pacc[slot][d][q] bf16, stats per q ----
  const int slot = (chunk_base(qsec) + c) * NH + h;
  ushort* ap = pacc + (size_t)slot * 4096;
#pragma unroll
  for (int nt = 0; nt < 4; ++nt)
#pragma unroll
    for (int r = 0; r < 4; ++r)
      ap[(nt * 16 + lg * 4 + r) * 64 + wid * 16 + lr] = f2bf(accy[nt][r]);
  if (lg == 0) {
    float* st = pstats + (size_t)slot * 128;
    st[(wid * 16 + lr) * 2 + 0] = mrun;
    st[(wid * 16 + lr) * 2 + 1] = dl;
  }
}

// ---------------------------------------------------------------------------
// Merge partials ([d][q] bf16) -> y[t][h*64+d] bf16.  nch <= 4.
// ---------------------------------------------------------------------------
__global__ __launch_bounds__(256) void attn_merge_kernel(
    const ushort* __restrict__ pacc, const float* __restrict__ pstats,
    ushort* __restrict__ y) {
  const int qsec = blockIdx.x, h = blockIdx.y;
  const int tid = threadIdx.x;
  const int w = tid >> 6, q = tid & 63;
  const int nch = (qsec >> 3) + 1;
  const int sbase = chunk_base(qsec);
  __shared__ float Lt[64][65];   // [d][q]

  float M = -INFINITY;
  for (int cc = 0; cc < nch; ++cc)
    M = fmaxf(M, pstats[(size_t)((sbase + cc) * NH + h) * 128 + q * 2]);
  float D = 0.f;
  for (int cc = 0; cc < nch; ++cc) {
    const float* st = pstats + (size_t)((sbase + cc) * NH + h) * 128 + q * 2;
    D += __expf(st[0] - M) * st[1];
  }
  const float invD = 1.f / D;

  float val[16];
#pragma unroll
  for (int j = 0; j < 16; ++j) val[j] = 0.f;
  for (int cc = 0; cc < nch; ++cc) {
    const int slot = (sbase + cc) * NH + h;
    const float cw = __expf(pstats[(size_t)slot * 128 + q * 2] - M) * invD;
    const ushort* ap = pacc + (size_t)slot * 4096 + w * 16 * 64 + q;
#pragma unroll
    for (int j = 0; j < 16; ++j) val[j] += cw * bf2f(ap[j * 64]);
  }
#pragma unroll
  for (int j = 0; j < 16; ++j) Lt[w * 16 + j][q] = val[j];
  __syncthreads();

  const int d = tid & 63;
#pragma unroll
  for (int j = 0; j < 16; ++j) {
    const int qq = w * 16 + j;
    y[(size_t)(qsec * 64 + qq) * CC + h * HDIM + d] = f2bf(Lt[d][qq]);
  }
}

// ---------------------------------------------------------------------------
extern "C" void kernel_launch(void* const* d_in, const int* in_sizes, int n_in,
                              void* d_out, int out_size, void* d_ws, size_t ws_size,
                              hipStream_t stream) {
  const float* x      = (const float*)d_in[0];
  // d_in[1] = is_mem: deterministic (t%64==63), recomputed in-kernel.
  const float* w_qkv  = (const float*)d_in[2];
  const float* b_qkv  = (const float*)d_in[3];
  const float* w_proj = (const float*)d_in[4];
  const float* b_proj = (const float*)d_in[5];
  float* out = (float*)d_out;

  // ws layout (bf16 elems unless noted). xb/wqkvT alias pacc (dead once the
  // qkv GEMM completes; stream is serial). pacc = 960*4096*2 = 7.86 MB >
  // xb+wqkvT = 6.7 MB, so the alias still fits.
  ushort* wprojT = (ushort*)d_ws;                     // 768 x 768
  ushort* qkvb   = wprojT + (size_t)CC * CC;          // 2048 x 2304
  ushort* vT     = qkvb + (size_t)TT * QKVLD;         // 768 x 2048
  ushort* y      = vT + (size_t)CC * TT;              // 2048 x 768
  ushort* pacc   = y + (size_t)TT * CC;               // 960 x 4096 bf16
  float*  pstats = (float*)(pacc + (size_t)NSLOTS * 4096);  // 960 x 128 f32
  ushort* xb     = pacc;                              // alias: 2048 x 768
  ushort* wqkvT  = xb + (size_t)TT * CC;              // alias: 2304 x 768

  // fused prep: convert x + both weight transposes
  prep_kernel<<<1344, 256, 0, stream>>>(x, w_qkv, w_proj, xb, wqkvT, wprojT);

  // qkv = xb @ wqkvT^T + b_qkv  (bf16 out, Q scaled, V transposed)
  gemm_bt_bf16_kernel<<<dim3(QKVLD / 64, TT / 64), 256, 0, stream>>>(
      xb, wqkvT, b_qkv, qkvb, vT, nullptr, TT, QKVLD, CC);

  // chunked landmark attention + merge
  attn_chunk_kernel<<<dim3(NCHMAX, NSEC, NH), 256, 0, stream>>>(
      qkvb, vT, pacc, pstats);
  attn_merge_kernel<<<dim3(NSEC, NH), 256, 0, stream>>>(pacc, pstats, y);

  // out = y @ wprojT^T + b_proj  (f32 out)
  gemm_bt_bf16_kernel<<<dim3(CC / 64, TT / 64), 256, 0, stream>>>(
      y, wprojT, b_proj, nullptr, nullptr, out, TT, CC, CC);
}